// Round 10
// baseline (796.918 us; speedup 1.0000x reference)
//
#include <hip/hip_runtime.h>
#include <hip/hip_bf16.h>

// Problem constants
#define N_ROWS 8192
#define DIM    2048
#define NCLS   751
#define NPAD   768     // wc padded rows (6*128)
#define KNN    6       // K+1 neighbors (incl self)
#define NCAND  12      // rescore candidates (gap(6,12) >> bf16 quant error)
#define GAP_THRESH 1.25e-3f   // bf16 rank-6/7 gap above which top-6 set is exact

typedef __attribute__((ext_vector_type(8))) short bf16x8;
typedef __attribute__((ext_vector_type(4))) float f32x4;

// ---------------------------------------------------------------------------
// async global->LDS, 16B per lane. LDS dest must be wave-uniform base + lane*16.
__device__ __forceinline__ void async_ld16(const __hip_bfloat16* g, __hip_bfloat16* l) {
    __builtin_amdgcn_global_load_lds(
        (__attribute__((address_space(1))) void*)(g),
        (__attribute__((address_space(3))) void*)(l), 16, 0, 0);
}

__device__ __forceinline__ float bf16_to_f32(short s) {
    union { float f; unsigned u; } cv;
    cv.u = ((unsigned)(unsigned short)s) << 16;
    return cv.f;
}

// ---------------------------------------------------------------------------
// Fused prep: blocks [0,8192) = row L2 norms (f64) + bf16 normalized rows;
// blocks [8192,16384) = w1/w2 f32->bf16 (4096 blocks each).
__global__ void prep_kernel(const float* __restrict__ x,
                            __hip_bfloat16* __restrict__ xnb,
                            double* __restrict__ invnorm,
                            const float* __restrict__ w1,
                            const float* __restrict__ w2,
                            __hip_bfloat16* __restrict__ w1b,
                            __hip_bfloat16* __restrict__ w2b) {
    int b = blockIdx.x, tid = threadIdx.x;          // 256 threads
    if (b < N_ROWS) {
        int row = b;
        const float4* xr4 = (const float4*)(x + (size_t)row * DIM);
        float4 v0 = xr4[tid], v1 = xr4[tid + 256];
        double s = (double)v0.x * v0.x + (double)v0.y * v0.y +
                   (double)v0.z * v0.z + (double)v0.w * v0.w +
                   (double)v1.x * v1.x + (double)v1.y * v1.y +
                   (double)v1.z * v1.z + (double)v1.w * v1.w;
        __shared__ double red[256];
        red[tid] = s; __syncthreads();
        for (int off = 128; off; off >>= 1) {
            if (tid < off) red[tid] += red[tid + off];
            __syncthreads();
        }
        double norm = sqrt(red[0]);
        if (norm < 1e-12) norm = 1e-12;
        double inv = 1.0 / norm;
        if (tid == 0) invnorm[row] = inv;
        float invf = (float)inv;
        __hip_bfloat16* o0 = xnb + (size_t)row * DIM + tid * 4;
        o0[0] = __float2bfloat16(v0.x * invf);
        o0[1] = __float2bfloat16(v0.y * invf);
        o0[2] = __float2bfloat16(v0.z * invf);
        o0[3] = __float2bfloat16(v0.w * invf);
        __hip_bfloat16* o1 = o0 + 1024;
        o1[0] = __float2bfloat16(v1.x * invf);
        o1[1] = __float2bfloat16(v1.y * invf);
        o1[2] = __float2bfloat16(v1.z * invf);
        o1[3] = __float2bfloat16(v1.w * invf);
    } else {
        int bb = b - N_ROWS;                        // 0..8191
        const float* src = (bb < 4096) ? w1 : w2;
        __hip_bfloat16* dst = (bb < 4096) ? w1b : w2b;
        int i = (bb & 4095) * 256 + tid;
        float4 v = ((const float4*)src)[i];
        __hip_bfloat16* o = dst + (size_t)i * 4;
        o[0] = __float2bfloat16(v.x); o[1] = __float2bfloat16(v.y);
        o[2] = __float2bfloat16(v.z); o[3] = __float2bfloat16(v.w);
    }
}

// ===========================================================================
// Tile engine (R3/R8 schedule -- measured plateau; do not touch).
// BM x 256 tile, BK=64, 8 waves (2Mx4N, per-wave BM/2 x 64), double-buffered
// LDS, 4 phases / K-step, 2 barriers / K-step. ds_reads for phase p+1 issue
// right after phase p's MFMA cluster with NO hand lgkmcnt -- compiler inserts
// fine-grained per-operand lgkm waits. Counted vmcnt per R3 FIFO ledger.
// Accumulation per element: kt-ascending, s-ascending -> bit-identical
// output across BM variants (verified: absmax 0.001953125).
// EPI: 0 = syrk store (direct + LDS-transposed)   1 = relu(v+bias)->bf16
//      4 = v+bias->bf16 + BN column stats
//      5 = v+bias->fp32, col<ncols guard, row stride ldc (classifier)
// ===========================================================================
template <int BM, int EPI>
__device__ __forceinline__ void tile_engine(
    const __hip_bfloat16* __restrict__ Aptr,
    const __hip_bfloat16* __restrict__ Bptr,
    char* __restrict__ smem,
    size_t bm, size_t bn,
    __hip_bfloat16* __restrict__ S,
    void* __restrict__ Cv,
    const float* __restrict__ bias,
    float* __restrict__ stats,
    int ldc, int ncols)
{
    constexpr int MI = BM / 32;                     // 8 or 4
    constexpr size_t ABYTES = (size_t)BM * 128;     // A tile bytes (BM x 64 bf16)
    constexpr size_t BUFS = ABYTES + 32768;         // + B tile (256 x 64 bf16)
    const int tid  = threadIdx.x;                   // 512 threads
    const int wave = tid >> 6, lane = tid & 63;
    const int wm = (wave >> 2) * (BM / 2), wn = (wave & 3) * 64;
    const int quad = lane >> 4, l15 = lane & 15;

    // staging: thread's fixed row/chunk within a 64-row pass
    const int srow = tid >> 3;                      // 0..63
    const int gsw  = ((tid & 7) ^ (srow & 7)) * 8;  // swizzled k-chunk (inverse of read)

    auto Asbuf = [&](int c) { return (__hip_bfloat16*)(smem + c * BUFS); };
    auto Bsbuf = [&](int c) { return (__hip_bfloat16*)(smem + c * BUFS + ABYTES); };

    auto arow = [&](int p) -> int {
        if constexpr (BM == 256) return (p << 6) + srow;
        else return (srow & 31) + ((srow >> 5) << 6) + (p << 5);
    };
    auto stageA = [&](int c, int p, size_t kb) {
        int gr = arow(p);
        async_ld16(Aptr + (bm + gr) * (size_t)DIM + kb + gsw,
                   Asbuf(c) + gr * 64 + (tid & 7) * 8);
    };
    auto stageB = [&](int c, int j, size_t kb) {
        async_ld16(Bptr + (bn + (j << 6) + srow) * (size_t)DIM + kb + gsw,
                   Bsbuf(c) + (j << 12) + tid * 8);
    };

    f32x4 acc[MI][4];
#pragma unroll
    for (int mi = 0; mi < MI; ++mi)
#pragma unroll
        for (int ni = 0; ni < 4; ++ni)
            acc[mi][ni] = (f32x4){0.f, 0.f, 0.f, 0.f};

    constexpr int KT = DIM / 64;                    // 32 K-steps

    // ---- prologue: stage tile 0 into buf 0 (A-last pass(es) issued LAST)
    {
        stageB(0, 0, 0); stageB(0, 1, 0); stageB(0, 2, 0); stageB(0, 3, 0);
        if constexpr (BM == 256) {
            stageA(0, 0, 0); stageA(0, 2, 0); stageA(0, 1, 0); stageA(0, 3, 0);
            asm volatile("s_waitcnt vmcnt(2)" ::: "memory");
        } else {
            stageA(0, 0, 0); stageA(0, 1, 0);
            asm volatile("s_waitcnt vmcnt(1)" ::: "memory");
        }
        __builtin_amdgcn_s_barrier();
        __builtin_amdgcn_sched_barrier(0);
    }

#pragma unroll 1
    for (int kt = 0; kt < KT; ++kt) {
        const int cur = kt & 1;
        __hip_bfloat16* As = Asbuf(cur);
        __hip_bfloat16* Bs = Bsbuf(cur);
        const int nb = cur ^ 1;
        const bool st = (kt < KT - 1);
        const size_t kb = (size_t)(kt + 1) * 64;

        bf16x8 af0[2][MI / 2], af1[2][MI / 2], b0[2][2], b1[2][2];

        // ---------------- P0: read af0 + b0; stage B{0,1}; MFMA af0 x b0
#pragma unroll
        for (int s = 0; s < 2; ++s) {
#pragma unroll
            for (int m = 0; m < MI / 2; ++m) {
                int rr = wm + m * 16 + l15;
                af0[s][m] = *(const bf16x8*)&As[(rr * 8 + ((s * 4 + quad) ^ (rr & 7))) * 8];
            }
#pragma unroll
            for (int n = 0; n < 2; ++n) {
                int rr = wn + n * 16 + l15;
                b0[s][n] = *(const bf16x8*)&Bs[(rr * 8 + ((s * 4 + quad) ^ (rr & 7))) * 8];
            }
        }
        if (st) { stageB(nb, 0, kb); stageB(nb, 1, kb); }
        __builtin_amdgcn_s_setprio(1);
#pragma unroll
        for (int s = 0; s < 2; ++s)
#pragma unroll
            for (int m = 0; m < MI / 2; ++m)
#pragma unroll
                for (int n = 0; n < 2; ++n)
                    acc[m][n] = __builtin_amdgcn_mfma_f32_16x16x32_bf16(
                        af0[s][m], b0[s][n], acc[m][n], 0, 0, 0);
        __builtin_amdgcn_s_setprio(0);
        if (st) { asm volatile("s_waitcnt vmcnt(2)" ::: "memory"); }
        else    { asm volatile("s_waitcnt vmcnt(0)" ::: "memory"); }
        __builtin_amdgcn_s_barrier();
        __builtin_amdgcn_sched_barrier(0);

        // ---------------- P1: read af1; stage B{2,3}; MFMA af1 x b0
#pragma unroll
        for (int s = 0; s < 2; ++s)
#pragma unroll
            for (int m = 0; m < MI / 2; ++m) {
                int rr = wm + (BM / 4) + m * 16 + l15;
                af1[s][m] = *(const bf16x8*)&As[(rr * 8 + ((s * 4 + quad) ^ (rr & 7))) * 8];
            }
        if (st) { stageB(nb, 2, kb); stageB(nb, 3, kb); }
        __builtin_amdgcn_s_setprio(1);
#pragma unroll
        for (int s = 0; s < 2; ++s)
#pragma unroll
            for (int m = 0; m < MI / 2; ++m)
#pragma unroll
                for (int n = 0; n < 2; ++n)
                    acc[MI / 2 + m][n] = __builtin_amdgcn_mfma_f32_16x16x32_bf16(
                        af1[s][m], b0[s][n], acc[MI / 2 + m][n], 0, 0, 0);
        __builtin_amdgcn_s_setprio(0);

        // ---------------- P2: read b1; stage A{0,2}; MFMA af1 x b1
#pragma unroll
        for (int s = 0; s < 2; ++s)
#pragma unroll
            for (int n = 0; n < 2; ++n) {
                int rr = wn + 32 + n * 16 + l15;
                b1[s][n] = *(const bf16x8*)&Bs[(rr * 8 + ((s * 4 + quad) ^ (rr & 7))) * 8];
            }
        if (st) {
            if constexpr (BM == 256) { stageA(nb, 0, kb); stageA(nb, 2, kb); }
            else                     { stageA(nb, 0, kb); }
        }
        __builtin_amdgcn_s_setprio(1);
#pragma unroll
        for (int s = 0; s < 2; ++s)
#pragma unroll
            for (int m = 0; m < MI / 2; ++m)
#pragma unroll
                for (int n = 0; n < 2; ++n)
                    acc[MI / 2 + m][2 + n] = __builtin_amdgcn_mfma_f32_16x16x32_bf16(
                        af1[s][m], b1[s][n], acc[MI / 2 + m][2 + n], 0, 0, 0);
        __builtin_amdgcn_s_setprio(0);

        // ---------------- P3: stage A{1,3}; MFMA af0 x b1; close
        if (st) {
            if constexpr (BM == 256) { stageA(nb, 1, kb); stageA(nb, 3, kb); }
            else                     { stageA(nb, 1, kb); }
        }
        __builtin_amdgcn_s_setprio(1);
#pragma unroll
        for (int s = 0; s < 2; ++s)
#pragma unroll
            for (int m = 0; m < MI / 2; ++m)
#pragma unroll
                for (int n = 0; n < 2; ++n)
                    acc[m][2 + n] = __builtin_amdgcn_mfma_f32_16x16x32_bf16(
                        af0[s][m], b1[s][n], acc[m][2 + n], 0, 0, 0);
        __builtin_amdgcn_s_setprio(0);
        if (st) {
            if constexpr (BM == 256) { asm volatile("s_waitcnt vmcnt(2)" ::: "memory"); }
            else                     { asm volatile("s_waitcnt vmcnt(1)" ::: "memory"); }
        } else {
            asm volatile("s_waitcnt vmcnt(0)" ::: "memory");
        }
        __builtin_amdgcn_s_barrier();
        __builtin_amdgcn_sched_barrier(0);
    }

    // ---------------- epilogues
    if constexpr (EPI == 0) {
        // direct store (C/D layout: col=lane&15, row=quad*4+e)
#pragma unroll
        for (int mi = 0; mi < MI; ++mi)
#pragma unroll
            for (int ni = 0; ni < 4; ++ni)
#pragma unroll
                for (int e = 0; e < 4; ++e) {
                    size_t row = bm + wm + mi * 16 + quad * 4 + e;
                    size_t col = bn + wn + ni * 16 + l15;
                    S[row * N_ROWS + col] = __float2bfloat16(acc[mi][ni][e]);
                }
        // transposed tile via LDS (8 passes of 32 cols), vector stores
        __hip_bfloat16* T = (__hip_bfloat16*)smem;
        constexpr int TSTR = BM + 8;
#pragma unroll
        for (int p = 0; p < 8; ++p) {
            __syncthreads();
            if ((wave & 3) == (p >> 1)) {
#pragma unroll
                for (int nio = 0; nio < 2; ++nio) {
                    const int ni = (p & 1) * 2 + nio;
                    const int tc = ni * 16 + l15 - (p & 1) * 32;   // 0..31
#pragma unroll
                    for (int mi = 0; mi < MI; ++mi)
#pragma unroll
                        for (int e = 0; e < 4; ++e) {
                            int r = wm + mi * 16 + quad * 4 + e;
                            T[tc * TSTR + r] = __float2bfloat16(acc[mi][ni][e]);
                        }
                }
            }
            __syncthreads();
#pragma unroll
            for (int j2 = 0; j2 < BM / 128; ++j2) {
                int q = tid + 512 * j2;
                int tc = q / (BM / 8), r8 = (q % (BM / 8)) * 8;
                *(bf16x8*)&S[(bn + p * 32 + tc) * (size_t)N_ROWS + bm + r8] =
                    *(const bf16x8*)&T[tc * TSTR + r8];
            }
        }
    } else if constexpr (EPI == 5) {
#pragma unroll
        for (int mi = 0; mi < MI; ++mi)
#pragma unroll
            for (int ni = 0; ni < 4; ++ni)
#pragma unroll
                for (int e = 0; e < 4; ++e) {
                    size_t row = bm + wm + mi * 16 + quad * 4 + e;
                    int col = (int)(bn + wn + ni * 16 + l15);
                    float v = acc[mi][ni][e] + bias[col];
                    if (col < ncols)
                        ((float*)Cv)[row * (size_t)ldc + col] = v;
                }
    } else {
        float s1[4] = {0.f, 0.f, 0.f, 0.f}, s2[4] = {0.f, 0.f, 0.f, 0.f};
#pragma unroll
        for (int mi = 0; mi < MI; ++mi)
#pragma unroll
            for (int ni = 0; ni < 4; ++ni)
#pragma unroll
                for (int e = 0; e < 4; ++e) {
                    size_t row = bm + wm + mi * 16 + quad * 4 + e;
                    int col = (int)(bn + wn + ni * 16 + l15);
                    float v = acc[mi][ni][e] + bias[col];
                    if constexpr (EPI == 1) v = v > 0.f ? v : 0.f;
                    ((__hip_bfloat16*)Cv)[row * (size_t)DIM + col] = __float2bfloat16(v);
                    if constexpr (EPI == 4) { s1[ni] += v; s2[ni] += v * v; }
                }
        if constexpr (EPI == 4) {
            __syncthreads();
            float* sred = (float*)smem;     // [2 M-halves][256 cols][2 stats]
#pragma unroll
            for (int ni = 0; ni < 4; ++ni) {
                float a = s1[ni], bq = s2[ni];
                a += __shfl_xor(a, 16);  a += __shfl_xor(a, 32);
                bq += __shfl_xor(bq, 16); bq += __shfl_xor(bq, 32);
                if (lane < 16) {
                    int c = wn + ni * 16 + l15;
                    sred[((wave >> 2) * 256 + c) * 2 + 0] = a;
                    sred[((wave >> 2) * 256 + c) * 2 + 1] = bq;
                }
            }
            __syncthreads();
            if (tid < 256) {
                float ta = sred[tid * 2] + sred[(256 + tid) * 2];
                float tb = sred[tid * 2 + 1] + sred[(256 + tid) * 2 + 1];
                atomicAdd(&stats[bn + tid], ta);
                atomicAdd(&stats[DIM + bn + tid], tb);
            }
        }
    }
}

// ---------------------------------------------------------------------------
// Triangular symmetric GEMM. Grid = 560 blocks:
//   b in [0,64):  diagonal half-blocks 128x256 (spread mod 8 over XCDs)
//   b in [64,560): strict upper-triangle 256x256 tiles (496 = 8 x 62),
//     XCD-chunked (T1): XCD x gets fulls [62x, 62x+62).
__global__ __launch_bounds__(512, 2)
void gemm_syrk(const __hip_bfloat16* __restrict__ A,
               __hip_bfloat16* __restrict__ S) {
    __shared__ __align__(16) char smem[2 * (256 * 128 + 32768)];   // 128 KB
    int b = blockIdx.x;
    if (b < 64) {
        int ti = b >> 1, half = b & 1;
        tile_engine<128, 0>(A, A, smem,
                            (size_t)ti * 256 + (size_t)half * 128,
                            (size_t)ti * 256, S, nullptr, nullptr, nullptr, 0, 0);
    } else {
        int o = b - 64;
        int f = (o & 7) * 62 + (o >> 3);   // XCD-contiguous chunk of 496 fulls
        int bi = (int)((63.0 - sqrt(3969.0 - 8.0 * (double)f)) * 0.5);
        while (31 * (bi + 1) - (bi + 1) * bi / 2 <= f) ++bi;
        while (bi > 0 && 31 * bi - bi * (bi - 1) / 2 > f) --bi;
        int bj = bi + 1 + (f - (31 * bi - bi * (bi - 1) / 2));
        tile_engine<256, 0>(A, A, smem, (size_t)bi * 256, (size_t)bj * 256,
                            S, nullptr, nullptr, nullptr, 0, 0);
    }
}

// ---------------------------------------------------------------------------
// 256x256 NT GEMM via tile_engine (grid (DIM/256, N_ROWS/256) = 256 blocks =
// exactly 1 block/CU, no tail). EPI 1/4 as before.
template <int EPI>
__global__ __launch_bounds__(512, 2)
void gemm_nt_256(const __hip_bfloat16* __restrict__ A,
                 const __hip_bfloat16* __restrict__ B,
                 void* __restrict__ Cv,
                 const float* __restrict__ bias,
                 float* __restrict__ stats) {
    __shared__ __align__(16) char smem[2 * (256 * 128 + 32768)];   // 128 KB
    tile_engine<256, EPI>(A, B, smem,
                          (size_t)blockIdx.y * 256, (size_t)blockIdx.x * 256,
                          nullptr, Cv, bias, stats, 0, 0);
}

// ---------------------------------------------------------------------------
// Classifier GEMM on the same engine: out[8192,751] = z2b @ wcs^T + lb.
// BM=128 tile -> grid (NPAD/256=3, N_ROWS/128=64) = 192 blocks, 1 clean
// round. EPI=5: fp32 store, col<NCLS guard, row stride NCLS.
__global__ __launch_bounds__(512, 2)
void gemm_cls(const __hip_bfloat16* __restrict__ A,
              const __hip_bfloat16* __restrict__ B,
              float* __restrict__ out,
              const float* __restrict__ lb) {
    __shared__ __align__(16) char smem[2 * (128 * 128 + 32768)];   // 96 KB
    tile_engine<128, 5>(A, B, smem,
                        (size_t)blockIdx.y * 128, (size_t)blockIdx.x * 256,
                        nullptr, (void*)out, lb, nullptr, NCLS, NCLS);
}

// ---------------------------------------------------------------------------
// R10 topk: barrier-free, LDS-free, 4 independent waves per 256-thr block
// (row = blockIdx*4 + wave). Per wave:
//  (a) scan: per-lane top-6 of its 1024 elements (identical code to R9);
//  (b) selection: 12 rounds, each = per-lane best-of-6 (comparator v desc,
//      ix asc) -> wave butterfly argmax (same comparator) -> owner lane
//      (unique ix => unique owner, all slots hold real values since every
//      lane scans 1024 finite values) kills its slot. Two-level max under a
//      strict total order == R9's global 384-entry argmax, round by round.
//  (c) gap test on ranks 5/6 (wave-uniform).
//  (d) fused f64 rescore, identical k-pattern/butterfly/tie-breaks to R9.
// -> idx6 bit-identical to R9.
__global__ __launch_bounds__(256)
void topk_kernel(const __hip_bfloat16* __restrict__ S,
                 const float* __restrict__ x,
                 const double* __restrict__ invn,
                 int* __restrict__ idx6) {
    const int lane = threadIdx.x & 63;
    const int row = blockIdx.x * 4 + (threadIdx.x >> 6);
    const bf16x8* Sr8 = (const bf16x8*)(S + (size_t)row * N_ROWS);
    float bv[6]; int bi6[6];
#pragma unroll
    for (int t = 0; t < 6; ++t) { bv[t] = -1e30f; bi6[t] = -1; }
    float vmin = -1e30f;
    for (int it = 0; it < N_ROWS / (64 * 8); ++it) {
        int c8 = it * 64 + lane;
        bf16x8 v8 = Sr8[c8];
#pragma unroll
        for (int u = 0; u < 8; ++u) {
            float v = bf16_to_f32(v8[u]);
            if (v > vmin) {
                int ms = 0; float mv = bv[0];
#pragma unroll
                for (int t = 1; t < 6; ++t) if (bv[t] < mv) { mv = bv[t]; ms = t; }
                bv[ms] = v; bi6[ms] = c8 * 8 + u;
                vmin = bv[0];
#pragma unroll
                for (int t = 1; t < 6; ++t) vmin = fminf(vmin, bv[t]);
            }
        }
    }
    // ---- selection: 12 rounds of register/shuffle argmax
    int topi[NCAND];
    float tv5 = 0.f, tv6 = 0.f;
#pragma unroll
    for (int t = 0; t < NCAND; ++t) {
        float m = bv[0]; int ms = 0, mix = bi6[0];
#pragma unroll
        for (int u = 1; u < 6; ++u)
            if (bv[u] > m || (bv[u] == m && bi6[u] < mix)) { m = bv[u]; ms = u; mix = bi6[u]; }
        float wv = m; int wix = mix;
#pragma unroll
        for (int off = 32; off; off >>= 1) {
            float ov = __shfl_xor(wv, off);
            int   oi = __shfl_xor(wix, off);
            if (ov > wv || (ov == wv && oi < wix)) { wv = ov; wix = oi; }
        }
        if (wix == mix) bv[ms] = -1e30f;   // owner lane removes (ix unique)
        topi[t] = wix;
        if (t == KNN - 1) tv5 = wv;
        if (t == KNN)     tv6 = wv;
    }
    // ---- gap test (wave-uniform)
    if (tv5 - tv6 >= GAP_THRESH) {
        if (lane == 0) {
#pragma unroll
            for (int t = 0; t < KNN; ++t) idx6[row * KNN + t] = topi[t];
        }
        return;
    }
    // ---- fused exact rescore (bit-identical to R9's)
    float4 xr[8];
    const float4* xrow4 = (const float4*)(x + (size_t)row * DIM);
#pragma unroll
    for (int i = 0; i < 8; ++i) xr[i] = xrow4[lane + 64 * i];
    double vals[NCAND];
#pragma unroll
    for (int t = 0; t < NCAND; ++t) {
        int j = topi[t];
        if (j == row) { vals[t] = 1e30; continue; }   // self: rank 1 (uniform)
        const float4* xj4 = (const float4*)(x + (size_t)j * DIM);
        double s = 0.0;
#pragma unroll
        for (int i = 0; i < 8; ++i) {
            float4 a = xj4[lane + 64 * i], bq = xr[i];
            s += (double)a.x * bq.x + (double)a.y * bq.y +
                 (double)a.z * bq.z + (double)a.w * bq.w;
        }
#pragma unroll
        for (int off = 32; off; off >>= 1) s += __shfl_xor(s, off);
        vals[t] = s * invn[row] * invn[j];
    }
    if (lane == 0) {
        for (int t = 0; t < KNN; ++t) {
            int best = 0; double bvv = -1e300; int bji = 0x7fffffff;
#pragma unroll
            for (int e = 0; e < NCAND; ++e) {
                if (vals[e] > bvv || (vals[e] == bvv && topi[e] < bji)) {
                    bvv = vals[e]; best = e; bji = topi[e];
                }
            }
            idx6[row * KNN + t] = topi[best];
            vals[best] = -1e300;
        }
    }
}

// ---------------------------------------------------------------------------
// GIN aggregation with reciprocal mask: h0 = 1.3*x_i + sum reciprocal x_j -> bf16
__global__ void aggregate_kernel(const float* __restrict__ x,
                                 const int* __restrict__ idx6,
                                 __hip_bfloat16* __restrict__ h0) {
    int row = blockIdx.x, tid = threadIdx.x;   // 256 threads
    __shared__ int nb[KNN];
    __shared__ int fl[KNN];
    if (tid < KNN) {
        int j = idx6[row * KNN + tid];
        nb[tid] = j;
        int f = 0;
        for (int t = 0; t < KNN; ++t) if (idx6[j * KNN + t] == row) f = 1;
        fl[tid] = f;
    }
    __syncthreads();
    int f0 = tid * 8;
    const float4* xr4 = (const float4*)(x + (size_t)row * DIM + f0);
    float4 a0 = xr4[0], a1 = xr4[1];
    float acc[8] = {1.3f * a0.x, 1.3f * a0.y, 1.3f * a0.z, 1.3f * a0.w,
                    1.3f * a1.x, 1.3f * a1.y, 1.3f * a1.z, 1.3f * a1.w};
    for (int t = 0; t < KNN; ++t) {
        if (fl[t]) {
            const float4* xj4 = (const float4*)(x + (size_t)nb[t] * DIM + f0);
            float4 b0 = xj4[0], b1 = xj4[1];
            acc[0] += b0.x; acc[1] += b0.y; acc[2] += b0.z; acc[3] += b0.w;
            acc[4] += b1.x; acc[5] += b1.y; acc[6] += b1.z; acc[7] += b1.w;
        }
    }
#pragma unroll
    for (int u = 0; u < 8; ++u)
        h0[(size_t)row * DIM + f0 + u] = __float2bfloat16(acc[u]);
}

// ---------------------------------------------------------------------------
// Fold BN into classifier (bn_finalize fused in): per column k,
//   mean = s1/N, var = s2/N - mean^2, sc = gamma/sqrt(var+eps),
//   shift = beta - mean*sc;  wcs[c,k] = wc[c,k]*sc (bf16, zero-padded rows),
//   lb[c] = sum_k shift[k]*wc[c,k].
__global__ void wc_fold_kernel(const float* __restrict__ wc,
                               const float* __restrict__ stats,
                               const float* __restrict__ gamma,
                               const float* __restrict__ beta,
                               __hip_bfloat16* __restrict__ wcs,
                               float* __restrict__ lb) {
    int r = blockIdx.x, tid = threadIdx.x;          // 768 blocks x 256
    int k0 = tid * 8;
    float part = 0.f;
    if (r < NCLS) {
#pragma unroll
        for (int u = 0; u < 8; ++u) {
            int k = k0 + u;
            float mean = stats[k] * (1.0f / 8192.0f);
            float var  = stats[DIM + k] * (1.0f / 8192.0f) - mean * mean;
            float sc   = gamma[k] / sqrtf(var + 1e-5f);
            float sh   = beta[k] - mean * sc;
            float w = wc[(size_t)r * DIM + k];
            wcs[(size_t)r * DIM + k] = __float2bfloat16(w * sc);
            part += w * sh;
        }
    } else {
#pragma unroll
        for (int u = 0; u < 8; ++u)
            wcs[(size_t)r * DIM + k0 + u] = __float2bfloat16(0.f);
    }
    __shared__ float red[256];
    red[tid] = part; __syncthreads();
    for (int off = 128; off; off >>= 1) {
        if (tid < off) red[tid] += red[tid + off];
        __syncthreads();
    }
    if (tid == 0) lb[r] = red[0];
}

// ---------------------------------------------------------------------------
extern "C" void kernel_launch(void* const* d_in, const int* in_sizes, int n_in,
                              void* d_out, int out_size, void* d_ws, size_t ws_size,
                              hipStream_t stream) {
    const float* x     = (const float*)d_in[0];
    const float* w1    = (const float*)d_in[1];
    const float* b1    = (const float*)d_in[2];
    const float* w2    = (const float*)d_in[3];
    const float* b2    = (const float*)d_in[4];
    const float* gamma = (const float*)d_in[5];
    const float* beta  = (const float*)d_in[6];
    const float* wc    = (const float*)d_in[7];
    float* out = (float*)d_out;

    char* ws = (char*)d_ws;
    size_t off = 0;
    auto alloc = [&](size_t bytes) -> void* {
        void* p = ws + off;
        off += (bytes + 255) & ~(size_t)255;
        return p;
    };

    __hip_bfloat16* xnb  = (__hip_bfloat16*)alloc((size_t)N_ROWS * DIM * 2);    // 32 MB (reused: h0)
    __hip_bfloat16* S    = (__hip_bfloat16*)alloc((size_t)N_ROWS * N_ROWS * 2); // 128 MB (reused: z1, z2b)
    double*         invn = (double*)alloc((size_t)N_ROWS * 8);
    int*            idx6 = (int*)alloc((size_t)N_ROWS * KNN * 4);
    __hip_bfloat16* w1b  = (__hip_bfloat16*)alloc((size_t)DIM * DIM * 2);
    __hip_bfloat16* w2b  = (__hip_bfloat16*)alloc((size_t)DIM * DIM * 2);
    __hip_bfloat16* wcs  = (__hip_bfloat16*)alloc((size_t)NPAD * DIM * 2);
    float*          lb   = (float*)alloc((size_t)NPAD * 4);
    float*          stats = (float*)alloc((size_t)4 * DIM * 4);

    __hip_bfloat16* h0  = xnb;                          // xn dead after syrk
    __hip_bfloat16* z1  = S;                            // S dead after topk
    __hip_bfloat16* z2b = S + (size_t)N_ROWS * DIM;     // next 32 MB of S region

    hipMemsetAsync(stats, 0, 2 * DIM * sizeof(float), stream);

    // normalize + both weight conversions, one launch
    prep_kernel<<<2 * N_ROWS, 256, 0, stream>>>(x, xnb, invn, w1, w2, w1b, w2b);

    // S = xn xn^T: 64 diagonal half-blocks + 496 upper 256^2 tiles (XCD-chunked)
    gemm_syrk<<<560, 512, 0, stream>>>(xnb, S);

    // top-6 (+ fused exact rescore), 4 independent waves per block
    topk_kernel<<<N_ROWS / 4, 256, 0, stream>>>(S, x, invn, idx6);
    aggregate_kernel<<<N_ROWS, 256, 0, stream>>>(x, idx6, h0);

    // z1 = relu(h0 @ w1^T + b1)   [bf16]
    gemm_nt_256<1><<<dim3(DIM / 256, N_ROWS / 256), 512, 0, stream>>>(
        h0, w1b, (void*)z1, b1, nullptr);
    // z2b = h@w2^T + b2 [bf16] with fused BN column stats
    gemm_nt_256<4><<<dim3(DIM / 256, N_ROWS / 256), 512, 0, stream>>>(
        z1, w2b, (void*)z2b, b2, stats);

    // fold BN into classifier weights (bn_finalize fused)
    wc_fold_kernel<<<NPAD, 256, 0, stream>>>(wc, stats, gamma, beta, wcs, lb);

    // logits = (z2*scale+shift) @ wc^T = z2b @ wcs^T + lb   [fp32, col<751]
    gemm_cls<<<dim3(NPAD / 256, N_ROWS / 128), 512, 0, stream>>>(
        z2b, wcs, out, lb);
}

// Round 11
// 731.292 us; speedup vs baseline: 1.0897x; 1.0897x over previous
//
#include <hip/hip_runtime.h>
#include <hip/hip_bf16.h>

// Problem constants
#define N_ROWS 8192
#define DIM    2048
#define NCLS   751
#define NPAD   768     // wc padded rows (6*128)
#define KNN    6       // K+1 neighbors (incl self)
#define NCAND  12      // rescore candidates (gap(6,12) >> bf16 quant error)
#define GAP_THRESH 1.25e-3f   // bf16 rank-6/7 gap above which top-6 set is exact

typedef __attribute__((ext_vector_type(8))) short bf16x8;
typedef __attribute__((ext_vector_type(4))) float f32x4;

// ---------------------------------------------------------------------------
// async global->LDS, 16B per lane. LDS dest must be wave-uniform base + lane*16.
__device__ __forceinline__ void async_ld16(const __hip_bfloat16* g, __hip_bfloat16* l) {
    __builtin_amdgcn_global_load_lds(
        (__attribute__((address_space(1))) void*)(g),
        (__attribute__((address_space(3))) void*)(l), 16, 0, 0);
}

__device__ __forceinline__ float bf16_to_f32(short s) {
    union { float f; unsigned u; } cv;
    cv.u = ((unsigned)(unsigned short)s) << 16;
    return cv.f;
}

// ---------------------------------------------------------------------------
// Fused prep: blocks [0,8192) = row L2 norms (f64) + bf16 normalized rows;
// blocks [8192,16384) = w1/w2 f32->bf16 (4096 blocks each).
__global__ void prep_kernel(const float* __restrict__ x,
                            __hip_bfloat16* __restrict__ xnb,
                            double* __restrict__ invnorm,
                            const float* __restrict__ w1,
                            const float* __restrict__ w2,
                            __hip_bfloat16* __restrict__ w1b,
                            __hip_bfloat16* __restrict__ w2b) {
    int b = blockIdx.x, tid = threadIdx.x;          // 256 threads
    if (b < N_ROWS) {
        int row = b;
        const float4* xr4 = (const float4*)(x + (size_t)row * DIM);
        float4 v0 = xr4[tid], v1 = xr4[tid + 256];
        double s = (double)v0.x * v0.x + (double)v0.y * v0.y +
                   (double)v0.z * v0.z + (double)v0.w * v0.w +
                   (double)v1.x * v1.x + (double)v1.y * v1.y +
                   (double)v1.z * v1.z + (double)v1.w * v1.w;
        __shared__ double red[256];
        red[tid] = s; __syncthreads();
        for (int off = 128; off; off >>= 1) {
            if (tid < off) red[tid] += red[tid + off];
            __syncthreads();
        }
        double norm = sqrt(red[0]);
        if (norm < 1e-12) norm = 1e-12;
        double inv = 1.0 / norm;
        if (tid == 0) invnorm[row] = inv;
        float invf = (float)inv;
        __hip_bfloat16* o0 = xnb + (size_t)row * DIM + tid * 4;
        o0[0] = __float2bfloat16(v0.x * invf);
        o0[1] = __float2bfloat16(v0.y * invf);
        o0[2] = __float2bfloat16(v0.z * invf);
        o0[3] = __float2bfloat16(v0.w * invf);
        __hip_bfloat16* o1 = o0 + 1024;
        o1[0] = __float2bfloat16(v1.x * invf);
        o1[1] = __float2bfloat16(v1.y * invf);
        o1[2] = __float2bfloat16(v1.z * invf);
        o1[3] = __float2bfloat16(v1.w * invf);
    } else {
        int bb = b - N_ROWS;                        // 0..8191
        const float* src = (bb < 4096) ? w1 : w2;
        __hip_bfloat16* dst = (bb < 4096) ? w1b : w2b;
        int i = (bb & 4095) * 256 + tid;
        float4 v = ((const float4*)src)[i];
        __hip_bfloat16* o = dst + (size_t)i * 4;
        o[0] = __float2bfloat16(v.x); o[1] = __float2bfloat16(v.y);
        o[2] = __float2bfloat16(v.z); o[3] = __float2bfloat16(v.w);
    }
}

// ===========================================================================
// Tile engine (R3/R8 schedule -- measured plateau; do not touch).
// BM x 256 tile, BK=64, 8 waves (2Mx4N, per-wave BM/2 x 64), double-buffered
// LDS, 4 phases / K-step, 2 barriers / K-step. Counted vmcnt per R3 ledger.
// Accumulation per element: kt-ascending, s-ascending -> bit-identical
// output across BM variants (verified: absmax 0.001953125).
// EPI: 0 = syrk store (direct + LDS-transposed)   1 = relu(v+bias)->bf16
//      4 = v+bias->bf16 + BN column stats
//      5 = v+bias->fp32, col<ncols guard, row stride ldc (classifier)
// ===========================================================================
template <int BM, int EPI>
__device__ __forceinline__ void tile_engine(
    const __hip_bfloat16* __restrict__ Aptr,
    const __hip_bfloat16* __restrict__ Bptr,
    char* __restrict__ smem,
    size_t bm, size_t bn,
    __hip_bfloat16* __restrict__ S,
    void* __restrict__ Cv,
    const float* __restrict__ bias,
    float* __restrict__ stats,
    int ldc, int ncols)
{
    constexpr int MI = BM / 32;                     // 8 or 4
    constexpr size_t ABYTES = (size_t)BM * 128;     // A tile bytes (BM x 64 bf16)
    constexpr size_t BUFS = ABYTES + 32768;         // + B tile (256 x 64 bf16)
    const int tid  = threadIdx.x;                   // 512 threads
    const int wave = tid >> 6, lane = tid & 63;
    const int wm = (wave >> 2) * (BM / 2), wn = (wave & 3) * 64;
    const int quad = lane >> 4, l15 = lane & 15;

    // staging: thread's fixed row/chunk within a 64-row pass
    const int srow = tid >> 3;                      // 0..63
    const int gsw  = ((tid & 7) ^ (srow & 7)) * 8;  // swizzled k-chunk (inverse of read)

    auto Asbuf = [&](int c) { return (__hip_bfloat16*)(smem + c * BUFS); };
    auto Bsbuf = [&](int c) { return (__hip_bfloat16*)(smem + c * BUFS + ABYTES); };

    auto arow = [&](int p) -> int {
        if constexpr (BM == 256) return (p << 6) + srow;
        else return (srow & 31) + ((srow >> 5) << 6) + (p << 5);
    };
    auto stageA = [&](int c, int p, size_t kb) {
        int gr = arow(p);
        async_ld16(Aptr + (bm + gr) * (size_t)DIM + kb + gsw,
                   Asbuf(c) + gr * 64 + (tid & 7) * 8);
    };
    auto stageB = [&](int c, int j, size_t kb) {
        async_ld16(Bptr + (bn + (j << 6) + srow) * (size_t)DIM + kb + gsw,
                   Bsbuf(c) + (j << 12) + tid * 8);
    };

    f32x4 acc[MI][4];
#pragma unroll
    for (int mi = 0; mi < MI; ++mi)
#pragma unroll
        for (int ni = 0; ni < 4; ++ni)
            acc[mi][ni] = (f32x4){0.f, 0.f, 0.f, 0.f};

    constexpr int KT = DIM / 64;                    // 32 K-steps

    // ---- prologue: stage tile 0 into buf 0 (A-last pass(es) issued LAST)
    {
        stageB(0, 0, 0); stageB(0, 1, 0); stageB(0, 2, 0); stageB(0, 3, 0);
        if constexpr (BM == 256) {
            stageA(0, 0, 0); stageA(0, 2, 0); stageA(0, 1, 0); stageA(0, 3, 0);
            asm volatile("s_waitcnt vmcnt(2)" ::: "memory");
        } else {
            stageA(0, 0, 0); stageA(0, 1, 0);
            asm volatile("s_waitcnt vmcnt(1)" ::: "memory");
        }
        __builtin_amdgcn_s_barrier();
        __builtin_amdgcn_sched_barrier(0);
    }

#pragma unroll 1
    for (int kt = 0; kt < KT; ++kt) {
        const int cur = kt & 1;
        __hip_bfloat16* As = Asbuf(cur);
        __hip_bfloat16* Bs = Bsbuf(cur);
        const int nb = cur ^ 1;
        const bool st = (kt < KT - 1);
        const size_t kb = (size_t)(kt + 1) * 64;

        bf16x8 af0[2][MI / 2], af1[2][MI / 2], b0[2][2], b1[2][2];

        // ---------------- P0: read af0 + b0; stage B{0,1}; MFMA af0 x b0
#pragma unroll
        for (int s = 0; s < 2; ++s) {
#pragma unroll
            for (int m = 0; m < MI / 2; ++m) {
                int rr = wm + m * 16 + l15;
                af0[s][m] = *(const bf16x8*)&As[(rr * 8 + ((s * 4 + quad) ^ (rr & 7))) * 8];
            }
#pragma unroll
            for (int n = 0; n < 2; ++n) {
                int rr = wn + n * 16 + l15;
                b0[s][n] = *(const bf16x8*)&Bs[(rr * 8 + ((s * 4 + quad) ^ (rr & 7))) * 8];
            }
        }
        if (st) { stageB(nb, 0, kb); stageB(nb, 1, kb); }
        __builtin_amdgcn_s_setprio(1);
#pragma unroll
        for (int s = 0; s < 2; ++s)
#pragma unroll
            for (int m = 0; m < MI / 2; ++m)
#pragma unroll
                for (int n = 0; n < 2; ++n)
                    acc[m][n] = __builtin_amdgcn_mfma_f32_16x16x32_bf16(
                        af0[s][m], b0[s][n], acc[m][n], 0, 0, 0);
        __builtin_amdgcn_s_setprio(0);
        if (st) { asm volatile("s_waitcnt vmcnt(2)" ::: "memory"); }
        else    { asm volatile("s_waitcnt vmcnt(0)" ::: "memory"); }
        __builtin_amdgcn_s_barrier();
        __builtin_amdgcn_sched_barrier(0);

        // ---------------- P1: read af1; stage B{2,3}; MFMA af1 x b0
#pragma unroll
        for (int s = 0; s < 2; ++s)
#pragma unroll
            for (int m = 0; m < MI / 2; ++m) {
                int rr = wm + (BM / 4) + m * 16 + l15;
                af1[s][m] = *(const bf16x8*)&As[(rr * 8 + ((s * 4 + quad) ^ (rr & 7))) * 8];
            }
        if (st) { stageB(nb, 2, kb); stageB(nb, 3, kb); }
        __builtin_amdgcn_s_setprio(1);
#pragma unroll
        for (int s = 0; s < 2; ++s)
#pragma unroll
            for (int m = 0; m < MI / 2; ++m)
#pragma unroll
                for (int n = 0; n < 2; ++n)
                    acc[MI / 2 + m][n] = __builtin_amdgcn_mfma_f32_16x16x32_bf16(
                        af1[s][m], b0[s][n], acc[MI / 2 + m][n], 0, 0, 0);
        __builtin_amdgcn_s_setprio(0);

        // ---------------- P2: read b1; stage A{0,2}; MFMA af1 x b1
#pragma unroll
        for (int s = 0; s < 2; ++s)
#pragma unroll
            for (int n = 0; n < 2; ++n) {
                int rr = wn + 32 + n * 16 + l15;
                b1[s][n] = *(const bf16x8*)&Bs[(rr * 8 + ((s * 4 + quad) ^ (rr & 7))) * 8];
            }
        if (st) {
            if constexpr (BM == 256) { stageA(nb, 0, kb); stageA(nb, 2, kb); }
            else                     { stageA(nb, 0, kb); }
        }
        __builtin_amdgcn_s_setprio(1);
#pragma unroll
        for (int s = 0; s < 2; ++s)
#pragma unroll
            for (int m = 0; m < MI / 2; ++m)
#pragma unroll
                for (int n = 0; n < 2; ++n)
                    acc[MI / 2 + m][2 + n] = __builtin_amdgcn_mfma_f32_16x16x32_bf16(
                        af1[s][m], b1[s][n], acc[MI / 2 + m][2 + n], 0, 0, 0);
        __builtin_amdgcn_s_setprio(0);

        // ---------------- P3: stage A{1,3}; MFMA af0 x b1; close
        if (st) {
            if constexpr (BM == 256) { stageA(nb, 1, kb); stageA(nb, 3, kb); }
            else                     { stageA(nb, 1, kb); }
        }
        __builtin_amdgcn_s_setprio(1);
#pragma unroll
        for (int s = 0; s < 2; ++s)
#pragma unroll
            for (int m = 0; m < MI / 2; ++m)
#pragma unroll
                for (int n = 0; n < 2; ++n)
                    acc[m][2 + n] = __builtin_amdgcn_mfma_f32_16x16x32_bf16(
                        af0[s][m], b1[s][n], acc[m][2 + n], 0, 0, 0);
        __builtin_amdgcn_s_setprio(0);
        if (st) {
            if constexpr (BM == 256) { asm volatile("s_waitcnt vmcnt(2)" ::: "memory"); }
            else                     { asm volatile("s_waitcnt vmcnt(1)" ::: "memory"); }
        } else {
            asm volatile("s_waitcnt vmcnt(0)" ::: "memory");
        }
        __builtin_amdgcn_s_barrier();
        __builtin_amdgcn_sched_barrier(0);
    }

    // ---------------- epilogues
    if constexpr (EPI == 0) {
        // direct store (C/D layout: col=lane&15, row=quad*4+e)
#pragma unroll
        for (int mi = 0; mi < MI; ++mi)
#pragma unroll
            for (int ni = 0; ni < 4; ++ni)
#pragma unroll
                for (int e = 0; e < 4; ++e) {
                    size_t row = bm + wm + mi * 16 + quad * 4 + e;
                    size_t col = bn + wn + ni * 16 + l15;
                    S[row * N_ROWS + col] = __float2bfloat16(acc[mi][ni][e]);
                }
        // transposed tile via LDS (8 passes of 32 cols), vector stores
        __hip_bfloat16* T = (__hip_bfloat16*)smem;
        constexpr int TSTR = BM + 8;
#pragma unroll
        for (int p = 0; p < 8; ++p) {
            __syncthreads();
            if ((wave & 3) == (p >> 1)) {
#pragma unroll
                for (int nio = 0; nio < 2; ++nio) {
                    const int ni = (p & 1) * 2 + nio;
                    const int tc = ni * 16 + l15 - (p & 1) * 32;   // 0..31
#pragma unroll
                    for (int mi = 0; mi < MI; ++mi)
#pragma unroll
                        for (int e = 0; e < 4; ++e) {
                            int r = wm + mi * 16 + quad * 4 + e;
                            T[tc * TSTR + r] = __float2bfloat16(acc[mi][ni][e]);
                        }
                }
            }
            __syncthreads();
#pragma unroll
            for (int j2 = 0; j2 < BM / 128; ++j2) {
                int q = tid + 512 * j2;
                int tc = q / (BM / 8), r8 = (q % (BM / 8)) * 8;
                *(bf16x8*)&S[(bn + p * 32 + tc) * (size_t)N_ROWS + bm + r8] =
                    *(const bf16x8*)&T[tc * TSTR + r8];
            }
        }
    } else if constexpr (EPI == 5) {
#pragma unroll
        for (int mi = 0; mi < MI; ++mi)
#pragma unroll
            for (int ni = 0; ni < 4; ++ni)
#pragma unroll
                for (int e = 0; e < 4; ++e) {
                    size_t row = bm + wm + mi * 16 + quad * 4 + e;
                    int col = (int)(bn + wn + ni * 16 + l15);
                    float v = acc[mi][ni][e] + bias[col];
                    if (col < ncols)
                        ((float*)Cv)[row * (size_t)ldc + col] = v;
                }
    } else {
        float s1[4] = {0.f, 0.f, 0.f, 0.f}, s2[4] = {0.f, 0.f, 0.f, 0.f};
#pragma unroll
        for (int mi = 0; mi < MI; ++mi)
#pragma unroll
            for (int ni = 0; ni < 4; ++ni)
#pragma unroll
                for (int e = 0; e < 4; ++e) {
                    size_t row = bm + wm + mi * 16 + quad * 4 + e;
                    int col = (int)(bn + wn + ni * 16 + l15);
                    float v = acc[mi][ni][e] + bias[col];
                    if constexpr (EPI == 1) v = v > 0.f ? v : 0.f;
                    ((__hip_bfloat16*)Cv)[row * (size_t)DIM + col] = __float2bfloat16(v);
                    if constexpr (EPI == 4) { s1[ni] += v; s2[ni] += v * v; }
                }
        if constexpr (EPI == 4) {
            __syncthreads();
            float* sred = (float*)smem;     // [2 M-halves][256 cols][2 stats]
#pragma unroll
            for (int ni = 0; ni < 4; ++ni) {
                float a = s1[ni], bq = s2[ni];
                a += __shfl_xor(a, 16);  a += __shfl_xor(a, 32);
                bq += __shfl_xor(bq, 16); bq += __shfl_xor(bq, 32);
                if (lane < 16) {
                    int c = wn + ni * 16 + l15;
                    sred[((wave >> 2) * 256 + c) * 2 + 0] = a;
                    sred[((wave >> 2) * 256 + c) * 2 + 1] = bq;
                }
            }
            __syncthreads();
            if (tid < 256) {
                float ta = sred[tid * 2] + sred[(256 + tid) * 2];
                float tb = sred[tid * 2 + 1] + sred[(256 + tid) * 2 + 1];
                atomicAdd(&stats[bn + tid], ta);
                atomicAdd(&stats[DIM + bn + tid], tb);
            }
        }
    }
}

// ---------------------------------------------------------------------------
// Triangular symmetric GEMM. Grid = 560 blocks:
//   b in [0,64):  diagonal half-blocks 128x256 (spread mod 8 over XCDs)
//   b in [64,560): strict upper-triangle 256x256 tiles (496 = 8 x 62),
//     XCD-chunked (T1): XCD x gets fulls [62x, 62x+62).
__global__ __launch_bounds__(512, 2)
void gemm_syrk(const __hip_bfloat16* __restrict__ A,
               __hip_bfloat16* __restrict__ S) {
    __shared__ __align__(16) char smem[2 * (256 * 128 + 32768)];   // 128 KB
    int b = blockIdx.x;
    if (b < 64) {
        int ti = b >> 1, half = b & 1;
        tile_engine<128, 0>(A, A, smem,
                            (size_t)ti * 256 + (size_t)half * 128,
                            (size_t)ti * 256, S, nullptr, nullptr, nullptr, 0, 0);
    } else {
        int o = b - 64;
        int f = (o & 7) * 62 + (o >> 3);   // XCD-contiguous chunk of 496 fulls
        int bi = (int)((63.0 - sqrt(3969.0 - 8.0 * (double)f)) * 0.5);
        while (31 * (bi + 1) - (bi + 1) * bi / 2 <= f) ++bi;
        while (bi > 0 && 31 * bi - bi * (bi - 1) / 2 > f) --bi;
        int bj = bi + 1 + (f - (31 * bi - bi * (bi - 1) / 2));
        tile_engine<256, 0>(A, A, smem, (size_t)bi * 256, (size_t)bj * 256,
                            S, nullptr, nullptr, nullptr, 0, 0);
    }
}

// ---------------------------------------------------------------------------
// 256x256 NT GEMM via tile_engine (grid (DIM/256, N_ROWS/256) = 256 blocks =
// exactly 1 block/CU, no tail). EPI 1/4 as before.
template <int EPI>
__global__ __launch_bounds__(512, 2)
void gemm_nt_256(const __hip_bfloat16* __restrict__ A,
                 const __hip_bfloat16* __restrict__ B,
                 void* __restrict__ Cv,
                 const float* __restrict__ bias,
                 float* __restrict__ stats) {
    __shared__ __align__(16) char smem[2 * (256 * 128 + 32768)];   // 128 KB
    tile_engine<256, EPI>(A, B, smem,
                          (size_t)blockIdx.y * 256, (size_t)blockIdx.x * 256,
                          nullptr, Cv, bias, stats, 0, 0);
}

// ---------------------------------------------------------------------------
// Classifier GEMM on the same engine: out[8192,751] = z2b @ wcs^T + lb.
// BM=128 tile -> grid (NPAD/256=3, N_ROWS/128=64) = 192 blocks, 1 clean
// round. EPI=5: fp32 store, col<NCLS guard, row stride NCLS.
__global__ __launch_bounds__(512, 2)
void gemm_cls(const __hip_bfloat16* __restrict__ A,
              const __hip_bfloat16* __restrict__ B,
              float* __restrict__ out,
              const float* __restrict__ lb) {
    __shared__ __align__(16) char smem[2 * (128 * 128 + 32768)];   // 96 KB
    tile_engine<128, 5>(A, B, smem,
                        (size_t)blockIdx.y * 128, (size_t)blockIdx.x * 256,
                        nullptr, (void*)out, lb, nullptr, NCLS, NCLS);
}

// ---------------------------------------------------------------------------
// R11 topk: R9's per-row algorithm (LDS scan buffer + LDS 12-round selection,
// VGPR-light) repackaged as 4 waves per 256-thread block, one ROW PER WAVE
// with per-wave LDS slices. Barrier discipline: the post-scan barrier and the
// 12 selection-round barriers are executed uniformly by all 4 waves (fixed
// counts); the divergent tail (gap-test early-return + rescore) is entirely
// barrier-free (rescore = butterfly sums; lane-0 simv writes/reads are
// same-lane, in-order DS). Values, comparators, and tie-breaks identical to
// R9 -> idx6 bit-identical.
__global__ __launch_bounds__(256)
void topk_kernel(const __hip_bfloat16* __restrict__ S,
                 const float* __restrict__ x,
                 const double* __restrict__ invn,
                 int* __restrict__ idx6) {
    const int lane = threadIdx.x & 63;
    const int wv   = threadIdx.x >> 6;          // wave id 0..3
    const int row  = blockIdx.x * 4 + wv;
    const bf16x8* Sr8 = (const bf16x8*)(S + (size_t)row * N_ROWS);
    float bv[6]; int bi6[6];
#pragma unroll
    for (int t = 0; t < 6; ++t) { bv[t] = -1e30f; bi6[t] = -1; }
    float vmin = -1e30f;
    for (int it = 0; it < N_ROWS / (64 * 8); ++it) {
        int c8 = it * 64 + lane;
        bf16x8 v8 = Sr8[c8];
#pragma unroll
        for (int u = 0; u < 8; ++u) {
            float v = bf16_to_f32(v8[u]);
            if (v > vmin) {
                int ms = 0; float mv = bv[0];
#pragma unroll
                for (int t = 1; t < 6; ++t) if (bv[t] < mv) { mv = bv[t]; ms = t; }
                bv[ms] = v; bi6[ms] = c8 * 8 + u;
                vmin = bv[0];
#pragma unroll
                for (int t = 1; t < 6; ++t) vmin = fminf(vmin, bv[t]);
            }
        }
    }
    __shared__ float sv[4][384];
    __shared__ int   si[4][384];
    __shared__ float topv[4][NCAND];
    __shared__ int   topi[4][NCAND];
    __shared__ double simv[4][NCAND];
#pragma unroll
    for (int t = 0; t < 6; ++t) { sv[wv][lane * 6 + t] = bv[t]; si[wv][lane * 6 + t] = bi6[t]; }
    __syncthreads();
    for (int t = 0; t < NCAND; ++t) {           // fixed 12 rounds, uniform
        float m = -1e30f; int mpos = -1, midx = 0x7fffffff;
        for (int e = lane; e < 384; e += 64) {
            float v = sv[wv][e]; int ix = si[wv][e];
            if (v > m || (v == m && ix < midx)) { m = v; mpos = e; midx = ix; }
        }
#pragma unroll
        for (int off = 32; off; off >>= 1) {
            float ov = __shfl_xor(m, off);
            int   op = __shfl_xor(mpos, off);
            int   oi = __shfl_xor(midx, off);
            if (ov > m || (ov == m && oi < midx)) { m = ov; mpos = op; midx = oi; }
        }
        if (lane == 0) {
            topv[wv][t] = m; topi[wv][t] = midx;
            sv[wv][mpos] = -1e30f;
        }
        __syncthreads();
    }
    // ---- divergent tail: no more barriers below this line ----
    if (topv[wv][KNN - 1] - topv[wv][KNN] >= GAP_THRESH) {
        if (lane == 0) {
#pragma unroll
            for (int t = 0; t < KNN; ++t) idx6[row * KNN + t] = topi[wv][t];
        }
        return;
    }
    // fused exact rescore (bit-identical to R9: same k-pattern, butterfly,
    // invn product order, tie-breaks)
    float4 xr[8];
    const float4* xrow4 = (const float4*)(x + (size_t)row * DIM);
#pragma unroll
    for (int i = 0; i < 8; ++i) xr[i] = xrow4[lane + 64 * i];
    for (int t = 0; t < NCAND; ++t) {
        int j = topi[wv][t];
        if (j == row) { if (lane == 0) simv[wv][t] = 1e30; continue; }  // self: rank 1
        const float4* xj4 = (const float4*)(x + (size_t)j * DIM);
        double s = 0.0;
#pragma unroll
        for (int i = 0; i < 8; ++i) {
            float4 a = xj4[lane + 64 * i], bq = xr[i];
            s += (double)a.x * bq.x + (double)a.y * bq.y +
                 (double)a.z * bq.z + (double)a.w * bq.w;
        }
#pragma unroll
        for (int off = 32; off; off >>= 1) s += __shfl_xor(s, off);
        if (lane == 0) simv[wv][t] = s * invn[row] * invn[j];
    }
    if (lane == 0) {    // same-lane LDS write->read, in-order DS pipe
        double vals[NCAND]; int idxs[NCAND];
        for (int t = 0; t < NCAND; ++t) { vals[t] = simv[wv][t]; idxs[t] = topi[wv][t]; }
        for (int t = 0; t < KNN; ++t) {
            int best = 0; double bvv = -1e300; int bji = 0x7fffffff;
            for (int e = 0; e < NCAND; ++e) {
                if (vals[e] > bvv || (vals[e] == bvv && idxs[e] < bji)) {
                    bvv = vals[e]; best = e; bji = idxs[e];
                }
            }
            idx6[row * KNN + t] = idxs[best];
            vals[best] = -1e300;
        }
    }
}

// ---------------------------------------------------------------------------
// GIN aggregation with reciprocal mask: h0 = 1.3*x_i + sum reciprocal x_j -> bf16
__global__ void aggregate_kernel(const float* __restrict__ x,
                                 const int* __restrict__ idx6,
                                 __hip_bfloat16* __restrict__ h0) {
    int row = blockIdx.x, tid = threadIdx.x;   // 256 threads
    __shared__ int nb[KNN];
    __shared__ int fl[KNN];
    if (tid < KNN) {
        int j = idx6[row * KNN + tid];
        nb[tid] = j;
        int f = 0;
        for (int t = 0; t < KNN; ++t) if (idx6[j * KNN + t] == row) f = 1;
        fl[tid] = f;
    }
    __syncthreads();
    int f0 = tid * 8;
    const float4* xr4 = (const float4*)(x + (size_t)row * DIM + f0);
    float4 a0 = xr4[0], a1 = xr4[1];
    float acc[8] = {1.3f * a0.x, 1.3f * a0.y, 1.3f * a0.z, 1.3f * a0.w,
                    1.3f * a1.x, 1.3f * a1.y, 1.3f * a1.z, 1.3f * a1.w};
    for (int t = 0; t < KNN; ++t) {
        if (fl[t]) {
            const float4* xj4 = (const float4*)(x + (size_t)nb[t] * DIM + f0);
            float4 b0 = xj4[0], b1 = xj4[1];
            acc[0] += b0.x; acc[1] += b0.y; acc[2] += b0.z; acc[3] += b0.w;
            acc[4] += b1.x; acc[5] += b1.y; acc[6] += b1.z; acc[7] += b1.w;
        }
    }
#pragma unroll
    for (int u = 0; u < 8; ++u)
        h0[(size_t)row * DIM + f0 + u] = __float2bfloat16(acc[u]);
}

// ---------------------------------------------------------------------------
// Fold BN into classifier (bn_finalize fused in): per column k,
//   mean = s1/N, var = s2/N - mean^2, sc = gamma/sqrt(var+eps),
//   shift = beta - mean*sc;  wcs[c,k] = wc[c,k]*sc (bf16, zero-padded rows),
//   lb[c] = sum_k shift[k]*wc[c,k].
__global__ void wc_fold_kernel(const float* __restrict__ wc,
                               const float* __restrict__ stats,
                               const float* __restrict__ gamma,
                               const float* __restrict__ beta,
                               __hip_bfloat16* __restrict__ wcs,
                               float* __restrict__ lb) {
    int r = blockIdx.x, tid = threadIdx.x;          // 768 blocks x 256
    int k0 = tid * 8;
    float part = 0.f;
    if (r < NCLS) {
#pragma unroll
        for (int u = 0; u < 8; ++u) {
            int k = k0 + u;
            float mean = stats[k] * (1.0f / 8192.0f);
            float var  = stats[DIM + k] * (1.0f / 8192.0f) - mean * mean;
            float sc   = gamma[k] / sqrtf(var + 1e-5f);
            float sh   = beta[k] - mean * sc;
            float w = wc[(size_t)r * DIM + k];
            wcs[(size_t)r * DIM + k] = __float2bfloat16(w * sc);
            part += w * sh;
        }
    } else {
#pragma unroll
        for (int u = 0; u < 8; ++u)
            wcs[(size_t)r * DIM + k0 + u] = __float2bfloat16(0.f);
    }
    __shared__ float red[256];
    red[tid] = part; __syncthreads();
    for (int off = 128; off; off >>= 1) {
        if (tid < off) red[tid] += red[tid + off];
        __syncthreads();
    }
    if (tid == 0) lb[r] = red[0];
}

// ---------------------------------------------------------------------------
extern "C" void kernel_launch(void* const* d_in, const int* in_sizes, int n_in,
                              void* d_out, int out_size, void* d_ws, size_t ws_size,
                              hipStream_t stream) {
    const float* x     = (const float*)d_in[0];
    const float* w1    = (const float*)d_in[1];
    const float* b1    = (const float*)d_in[2];
    const float* w2    = (const float*)d_in[3];
    const float* b2    = (const float*)d_in[4];
    const float* gamma = (const float*)d_in[5];
    const float* beta  = (const float*)d_in[6];
    const float* wc    = (const float*)d_in[7];
    float* out = (float*)d_out;

    char* ws = (char*)d_ws;
    size_t off = 0;
    auto alloc = [&](size_t bytes) -> void* {
        void* p = ws + off;
        off += (bytes + 255) & ~(size_t)255;
        return p;
    };

    __hip_bfloat16* xnb  = (__hip_bfloat16*)alloc((size_t)N_ROWS * DIM * 2);    // 32 MB (reused: h0)
    __hip_bfloat16* S    = (__hip_bfloat16*)alloc((size_t)N_ROWS * N_ROWS * 2); // 128 MB (reused: z1, z2b)
    double*         invn = (double*)alloc((size_t)N_ROWS * 8);
    int*            idx6 = (int*)alloc((size_t)N_ROWS * KNN * 4);
    __hip_bfloat16* w1b  = (__hip_bfloat16*)alloc((size_t)DIM * DIM * 2);
    __hip_bfloat16* w2b  = (__hip_bfloat16*)alloc((size_t)DIM * DIM * 2);
    __hip_bfloat16* wcs  = (__hip_bfloat16*)alloc((size_t)NPAD * DIM * 2);
    float*          lb   = (float*)alloc((size_t)NPAD * 4);
    float*          stats = (float*)alloc((size_t)4 * DIM * 4);

    __hip_bfloat16* h0  = xnb;                          // xn dead after syrk
    __hip_bfloat16* z1  = S;                            // S dead after topk
    __hip_bfloat16* z2b = S + (size_t)N_ROWS * DIM;     // next 32 MB of S region

    hipMemsetAsync(stats, 0, 2 * DIM * sizeof(float), stream);

    // normalize + both weight conversions, one launch
    prep_kernel<<<2 * N_ROWS, 256, 0, stream>>>(x, xnb, invn, w1, w2, w1b, w2b);

    // S = xn xn^T: 64 diagonal half-blocks + 496 upper 256^2 tiles (XCD-chunked)
    gemm_syrk<<<560, 512, 0, stream>>>(xnb, S);

    // top-6 (+ fused exact rescore), 4 rows per block (1 per wave)
    topk_kernel<<<N_ROWS / 4, 256, 0, stream>>>(S, x, invn, idx6);
    aggregate_kernel<<<N_ROWS, 256, 0, stream>>>(x, idx6, h0);

    // z1 = relu(h0 @ w1^T + b1)   [bf16]
    gemm_nt_256<1><<<dim3(DIM / 256, N_ROWS / 256), 512, 0, stream>>>(
        h0, w1b, (void*)z1, b1, nullptr);
    // z2b = h@w2^T + b2 [bf16] with fused BN column stats
    gemm_nt_256<4><<<dim3(DIM / 256, N_ROWS / 256), 512, 0, stream>>>(
        z1, w2b, (void*)z2b, b2, stats);

    // fold BN into classifier weights (bn_finalize fused)
    wc_fold_kernel<<<NPAD, 256, 0, stream>>>(wc, stats, gamma, beta, wcs, lb);

    // logits = (z2*scale+shift) @ wc^T = z2b @ wcs^T + lb   [fp32, col<751]
    gemm_cls<<<dim3(NPAD / 256, N_ROWS / 128), 512, 0, stream>>>(
        z2b, wcs, out, lb);
}

// Round 12
// 657.337 us; speedup vs baseline: 1.2123x; 1.1125x over previous
//
#include <hip/hip_runtime.h>
#include <hip/hip_bf16.h>

// Problem constants
#define N_ROWS 8192
#define DIM    2048
#define NCLS   751
#define NPAD   768     // wc padded rows (6*128)
#define KNN    6       // K+1 neighbors (incl self)
#define NCAND  12      // rescore candidates (gap(6,12) >> bf16 quant error)
#define GAP_THRESH 1.25e-3f   // bf16 rank-6/7 gap above which top-6 set is exact

typedef __attribute__((ext_vector_type(8))) short bf16x8;
typedef __attribute__((ext_vector_type(4))) float f32x4;

// ---------------------------------------------------------------------------
// async global->LDS, 16B per lane. LDS dest must be wave-uniform base + lane*16.
__device__ __forceinline__ void async_ld16(const __hip_bfloat16* g, __hip_bfloat16* l) {
    __builtin_amdgcn_global_load_lds(
        (__attribute__((address_space(1))) void*)(g),
        (__attribute__((address_space(3))) void*)(l), 16, 0, 0);
}

__device__ __forceinline__ float bf16_to_f32(short s) {
    union { float f; unsigned u; } cv;
    cv.u = ((unsigned)(unsigned short)s) << 16;
    return cv.f;
}

// ---------------------------------------------------------------------------
// Fused prep: blocks [0,8192) = row L2 norms (f64) + bf16 normalized rows;
// blocks [8192,16384) = w1/w2 f32->bf16 (4096 blocks each).
__global__ void prep_kernel(const float* __restrict__ x,
                            __hip_bfloat16* __restrict__ xnb,
                            double* __restrict__ invnorm,
                            const float* __restrict__ w1,
                            const float* __restrict__ w2,
                            __hip_bfloat16* __restrict__ w1b,
                            __hip_bfloat16* __restrict__ w2b) {
    int b = blockIdx.x, tid = threadIdx.x;          // 256 threads
    if (b < N_ROWS) {
        int row = b;
        const float4* xr4 = (const float4*)(x + (size_t)row * DIM);
        float4 v0 = xr4[tid], v1 = xr4[tid + 256];
        double s = (double)v0.x * v0.x + (double)v0.y * v0.y +
                   (double)v0.z * v0.z + (double)v0.w * v0.w +
                   (double)v1.x * v1.x + (double)v1.y * v1.y +
                   (double)v1.z * v1.z + (double)v1.w * v1.w;
        __shared__ double red[256];
        red[tid] = s; __syncthreads();
        for (int off = 128; off; off >>= 1) {
            if (tid < off) red[tid] += red[tid + off];
            __syncthreads();
        }
        double norm = sqrt(red[0]);
        if (norm < 1e-12) norm = 1e-12;
        double inv = 1.0 / norm;
        if (tid == 0) invnorm[row] = inv;
        float invf = (float)inv;
        __hip_bfloat16* o0 = xnb + (size_t)row * DIM + tid * 4;
        o0[0] = __float2bfloat16(v0.x * invf);
        o0[1] = __float2bfloat16(v0.y * invf);
        o0[2] = __float2bfloat16(v0.z * invf);
        o0[3] = __float2bfloat16(v0.w * invf);
        __hip_bfloat16* o1 = o0 + 1024;
        o1[0] = __float2bfloat16(v1.x * invf);
        o1[1] = __float2bfloat16(v1.y * invf);
        o1[2] = __float2bfloat16(v1.z * invf);
        o1[3] = __float2bfloat16(v1.w * invf);
    } else {
        int bb = b - N_ROWS;                        // 0..8191
        const float* src = (bb < 4096) ? w1 : w2;
        __hip_bfloat16* dst = (bb < 4096) ? w1b : w2b;
        int i = (bb & 4095) * 256 + tid;
        float4 v = ((const float4*)src)[i];
        __hip_bfloat16* o = dst + (size_t)i * 4;
        o[0] = __float2bfloat16(v.x); o[1] = __float2bfloat16(v.y);
        o[2] = __float2bfloat16(v.z); o[3] = __float2bfloat16(v.w);
    }
}

// ===========================================================================
// Tile engine (R3/R8 schedule -- measured plateau; do not touch).
// BM x 256 tile, BK=64, 8 waves (2Mx4N, per-wave BM/2 x 64), double-buffered
// LDS, 4 phases / K-step, 2 barriers / K-step. Counted vmcnt per R3 ledger.
// Accumulation per element: kt-ascending, s-ascending -> bit-identical
// output across BM variants (verified: absmax 0.001953125).
// EPI: 0 = syrk store (direct + LDS-transposed)   1 = relu(v+bias)->bf16
//      4 = v+bias->bf16 + BN column stats
//      5 = v+bias->fp32, col<ncols guard, row stride ldc (classifier)
// ===========================================================================
template <int BM, int EPI>
__device__ __forceinline__ void tile_engine(
    const __hip_bfloat16* __restrict__ Aptr,
    const __hip_bfloat16* __restrict__ Bptr,
    char* __restrict__ smem,
    size_t bm, size_t bn,
    __hip_bfloat16* __restrict__ S,
    void* __restrict__ Cv,
    const float* __restrict__ bias,
    float* __restrict__ stats,
    int ldc, int ncols)
{
    constexpr int MI = BM / 32;                     // 8 or 4
    constexpr size_t ABYTES = (size_t)BM * 128;     // A tile bytes (BM x 64 bf16)
    constexpr size_t BUFS = ABYTES + 32768;         // + B tile (256 x 64 bf16)
    const int tid  = threadIdx.x;                   // 512 threads
    const int wave = tid >> 6, lane = tid & 63;
    const int wm = (wave >> 2) * (BM / 2), wn = (wave & 3) * 64;
    const int quad = lane >> 4, l15 = lane & 15;

    // staging: thread's fixed row/chunk within a 64-row pass
    const int srow = tid >> 3;                      // 0..63
    const int gsw  = ((tid & 7) ^ (srow & 7)) * 8;  // swizzled k-chunk (inverse of read)

    auto Asbuf = [&](int c) { return (__hip_bfloat16*)(smem + c * BUFS); };
    auto Bsbuf = [&](int c) { return (__hip_bfloat16*)(smem + c * BUFS + ABYTES); };

    auto arow = [&](int p) -> int {
        if constexpr (BM == 256) return (p << 6) + srow;
        else return (srow & 31) + ((srow >> 5) << 6) + (p << 5);
    };
    auto stageA = [&](int c, int p, size_t kb) {
        int gr = arow(p);
        async_ld16(Aptr + (bm + gr) * (size_t)DIM + kb + gsw,
                   Asbuf(c) + gr * 64 + (tid & 7) * 8);
    };
    auto stageB = [&](int c, int j, size_t kb) {
        async_ld16(Bptr + (bn + (j << 6) + srow) * (size_t)DIM + kb + gsw,
                   Bsbuf(c) + (j << 12) + tid * 8);
    };

    f32x4 acc[MI][4];
#pragma unroll
    for (int mi = 0; mi < MI; ++mi)
#pragma unroll
        for (int ni = 0; ni < 4; ++ni)
            acc[mi][ni] = (f32x4){0.f, 0.f, 0.f, 0.f};

    constexpr int KT = DIM / 64;                    // 32 K-steps

    // ---- prologue: stage tile 0 into buf 0 (A-last pass(es) issued LAST)
    {
        stageB(0, 0, 0); stageB(0, 1, 0); stageB(0, 2, 0); stageB(0, 3, 0);
        if constexpr (BM == 256) {
            stageA(0, 0, 0); stageA(0, 2, 0); stageA(0, 1, 0); stageA(0, 3, 0);
            asm volatile("s_waitcnt vmcnt(2)" ::: "memory");
        } else {
            stageA(0, 0, 0); stageA(0, 1, 0);
            asm volatile("s_waitcnt vmcnt(1)" ::: "memory");
        }
        __builtin_amdgcn_s_barrier();
        __builtin_amdgcn_sched_barrier(0);
    }

#pragma unroll 1
    for (int kt = 0; kt < KT; ++kt) {
        const int cur = kt & 1;
        __hip_bfloat16* As = Asbuf(cur);
        __hip_bfloat16* Bs = Bsbuf(cur);
        const int nb = cur ^ 1;
        const bool st = (kt < KT - 1);
        const size_t kb = (size_t)(kt + 1) * 64;

        bf16x8 af0[2][MI / 2], af1[2][MI / 2], b0[2][2], b1[2][2];

        // ---------------- P0: read af0 + b0; stage B{0,1}; MFMA af0 x b0
#pragma unroll
        for (int s = 0; s < 2; ++s) {
#pragma unroll
            for (int m = 0; m < MI / 2; ++m) {
                int rr = wm + m * 16 + l15;
                af0[s][m] = *(const bf16x8*)&As[(rr * 8 + ((s * 4 + quad) ^ (rr & 7))) * 8];
            }
#pragma unroll
            for (int n = 0; n < 2; ++n) {
                int rr = wn + n * 16 + l15;
                b0[s][n] = *(const bf16x8*)&Bs[(rr * 8 + ((s * 4 + quad) ^ (rr & 7))) * 8];
            }
        }
        if (st) { stageB(nb, 0, kb); stageB(nb, 1, kb); }
        __builtin_amdgcn_s_setprio(1);
#pragma unroll
        for (int s = 0; s < 2; ++s)
#pragma unroll
            for (int m = 0; m < MI / 2; ++m)
#pragma unroll
                for (int n = 0; n < 2; ++n)
                    acc[m][n] = __builtin_amdgcn_mfma_f32_16x16x32_bf16(
                        af0[s][m], b0[s][n], acc[m][n], 0, 0, 0);
        __builtin_amdgcn_s_setprio(0);
        if (st) { asm volatile("s_waitcnt vmcnt(2)" ::: "memory"); }
        else    { asm volatile("s_waitcnt vmcnt(0)" ::: "memory"); }
        __builtin_amdgcn_s_barrier();
        __builtin_amdgcn_sched_barrier(0);

        // ---------------- P1: read af1; stage B{2,3}; MFMA af1 x b0
#pragma unroll
        for (int s = 0; s < 2; ++s)
#pragma unroll
            for (int m = 0; m < MI / 2; ++m) {
                int rr = wm + (BM / 4) + m * 16 + l15;
                af1[s][m] = *(const bf16x8*)&As[(rr * 8 + ((s * 4 + quad) ^ (rr & 7))) * 8];
            }
        if (st) { stageB(nb, 2, kb); stageB(nb, 3, kb); }
        __builtin_amdgcn_s_setprio(1);
#pragma unroll
        for (int s = 0; s < 2; ++s)
#pragma unroll
            for (int m = 0; m < MI / 2; ++m)
#pragma unroll
                for (int n = 0; n < 2; ++n)
                    acc[MI / 2 + m][n] = __builtin_amdgcn_mfma_f32_16x16x32_bf16(
                        af1[s][m], b0[s][n], acc[MI / 2 + m][n], 0, 0, 0);
        __builtin_amdgcn_s_setprio(0);

        // ---------------- P2: read b1; stage A{0,2}; MFMA af1 x b1
#pragma unroll
        for (int s = 0; s < 2; ++s)
#pragma unroll
            for (int n = 0; n < 2; ++n) {
                int rr = wn + 32 + n * 16 + l15;
                b1[s][n] = *(const bf16x8*)&Bs[(rr * 8 + ((s * 4 + quad) ^ (rr & 7))) * 8];
            }
        if (st) {
            if constexpr (BM == 256) { stageA(nb, 0, kb); stageA(nb, 2, kb); }
            else                     { stageA(nb, 0, kb); }
        }
        __builtin_amdgcn_s_setprio(1);
#pragma unroll
        for (int s = 0; s < 2; ++s)
#pragma unroll
            for (int m = 0; m < MI / 2; ++m)
#pragma unroll
                for (int n = 0; n < 2; ++n)
                    acc[MI / 2 + m][2 + n] = __builtin_amdgcn_mfma_f32_16x16x32_bf16(
                        af1[s][m], b1[s][n], acc[MI / 2 + m][2 + n], 0, 0, 0);
        __builtin_amdgcn_s_setprio(0);

        // ---------------- P3: stage A{1,3}; MFMA af0 x b1; close
        if (st) {
            if constexpr (BM == 256) { stageA(nb, 1, kb); stageA(nb, 3, kb); }
            else                     { stageA(nb, 1, kb); }
        }
        __builtin_amdgcn_s_setprio(1);
#pragma unroll
        for (int s = 0; s < 2; ++s)
#pragma unroll
            for (int m = 0; m < MI / 2; ++m)
#pragma unroll
                for (int n = 0; n < 2; ++n)
                    acc[m][2 + n] = __builtin_amdgcn_mfma_f32_16x16x32_bf16(
                        af0[s][m], b1[s][n], acc[m][2 + n], 0, 0, 0);
        __builtin_amdgcn_s_setprio(0);
        if (st) {
            if constexpr (BM == 256) { asm volatile("s_waitcnt vmcnt(2)" ::: "memory"); }
            else                     { asm volatile("s_waitcnt vmcnt(1)" ::: "memory"); }
        } else {
            asm volatile("s_waitcnt vmcnt(0)" ::: "memory");
        }
        __builtin_amdgcn_s_barrier();
        __builtin_amdgcn_sched_barrier(0);
    }

    // ---------------- epilogues
    if constexpr (EPI == 0) {
        // direct store (C/D layout: col=lane&15, row=quad*4+e)
#pragma unroll
        for (int mi = 0; mi < MI; ++mi)
#pragma unroll
            for (int ni = 0; ni < 4; ++ni)
#pragma unroll
                for (int e = 0; e < 4; ++e) {
                    size_t row = bm + wm + mi * 16 + quad * 4 + e;
                    size_t col = bn + wn + ni * 16 + l15;
                    S[row * N_ROWS + col] = __float2bfloat16(acc[mi][ni][e]);
                }
        // transposed tile via LDS (8 passes of 32 cols), vector stores
        __hip_bfloat16* T = (__hip_bfloat16*)smem;
        constexpr int TSTR = BM + 8;
#pragma unroll
        for (int p = 0; p < 8; ++p) {
            __syncthreads();
            if ((wave & 3) == (p >> 1)) {
#pragma unroll
                for (int nio = 0; nio < 2; ++nio) {
                    const int ni = (p & 1) * 2 + nio;
                    const int tc = ni * 16 + l15 - (p & 1) * 32;   // 0..31
#pragma unroll
                    for (int mi = 0; mi < MI; ++mi)
#pragma unroll
                        for (int e = 0; e < 4; ++e) {
                            int r = wm + mi * 16 + quad * 4 + e;
                            T[tc * TSTR + r] = __float2bfloat16(acc[mi][ni][e]);
                        }
                }
            }
            __syncthreads();
#pragma unroll
            for (int j2 = 0; j2 < BM / 128; ++j2) {
                int q = tid + 512 * j2;
                int tc = q / (BM / 8), r8 = (q % (BM / 8)) * 8;
                *(bf16x8*)&S[(bn + p * 32 + tc) * (size_t)N_ROWS + bm + r8] =
                    *(const bf16x8*)&T[tc * TSTR + r8];
            }
        }
    } else if constexpr (EPI == 5) {
#pragma unroll
        for (int mi = 0; mi < MI; ++mi)
#pragma unroll
            for (int ni = 0; ni < 4; ++ni)
#pragma unroll
                for (int e = 0; e < 4; ++e) {
                    size_t row = bm + wm + mi * 16 + quad * 4 + e;
                    int col = (int)(bn + wn + ni * 16 + l15);
                    float v = acc[mi][ni][e] + bias[col];
                    if (col < ncols)
                        ((float*)Cv)[row * (size_t)ldc + col] = v;
                }
    } else {
        float s1[4] = {0.f, 0.f, 0.f, 0.f}, s2[4] = {0.f, 0.f, 0.f, 0.f};
#pragma unroll
        for (int mi = 0; mi < MI; ++mi)
#pragma unroll
            for (int ni = 0; ni < 4; ++ni)
#pragma unroll
                for (int e = 0; e < 4; ++e) {
                    size_t row = bm + wm + mi * 16 + quad * 4 + e;
                    int col = (int)(bn + wn + ni * 16 + l15);
                    float v = acc[mi][ni][e] + bias[col];
                    if constexpr (EPI == 1) v = v > 0.f ? v : 0.f;
                    ((__hip_bfloat16*)Cv)[row * (size_t)DIM + col] = __float2bfloat16(v);
                    if constexpr (EPI == 4) { s1[ni] += v; s2[ni] += v * v; }
                }
        if constexpr (EPI == 4) {
            __syncthreads();
            float* sred = (float*)smem;     // [2 M-halves][256 cols][2 stats]
#pragma unroll
            for (int ni = 0; ni < 4; ++ni) {
                float a = s1[ni], bq = s2[ni];
                a += __shfl_xor(a, 16);  a += __shfl_xor(a, 32);
                bq += __shfl_xor(bq, 16); bq += __shfl_xor(bq, 32);
                if (lane < 16) {
                    int c = wn + ni * 16 + l15;
                    sred[((wave >> 2) * 256 + c) * 2 + 0] = a;
                    sred[((wave >> 2) * 256 + c) * 2 + 1] = bq;
                }
            }
            __syncthreads();
            if (tid < 256) {
                float ta = sred[tid * 2] + sred[(256 + tid) * 2];
                float tb = sred[tid * 2 + 1] + sred[(256 + tid) * 2 + 1];
                atomicAdd(&stats[bn + tid], ta);
                atomicAdd(&stats[DIM + bn + tid], tb);
            }
        }
    }
}

// ---------------------------------------------------------------------------
// Triangular symmetric GEMM. Grid = 560 blocks:
//   b in [0,64):  diagonal half-blocks 128x256 (spread mod 8 over XCDs)
//   b in [64,560): strict upper-triangle 256x256 tiles (496 = 8 x 62),
//     XCD-chunked (T1): XCD x gets fulls [62x, 62x+62).
__global__ __launch_bounds__(512, 2)
void gemm_syrk(const __hip_bfloat16* __restrict__ A,
               __hip_bfloat16* __restrict__ S) {
    __shared__ __align__(16) char smem[2 * (256 * 128 + 32768)];   // 128 KB
    int b = blockIdx.x;
    if (b < 64) {
        int ti = b >> 1, half = b & 1;
        tile_engine<128, 0>(A, A, smem,
                            (size_t)ti * 256 + (size_t)half * 128,
                            (size_t)ti * 256, S, nullptr, nullptr, nullptr, 0, 0);
    } else {
        int o = b - 64;
        int f = (o & 7) * 62 + (o >> 3);   // XCD-contiguous chunk of 496 fulls
        int bi = (int)((63.0 - sqrt(3969.0 - 8.0 * (double)f)) * 0.5);
        while (31 * (bi + 1) - (bi + 1) * bi / 2 <= f) ++bi;
        while (bi > 0 && 31 * bi - bi * (bi - 1) / 2 > f) --bi;
        int bj = bi + 1 + (f - (31 * bi - bi * (bi - 1) / 2));
        tile_engine<256, 0>(A, A, smem, (size_t)bi * 256, (size_t)bj * 256,
                            S, nullptr, nullptr, nullptr, 0, 0);
    }
}

// ---------------------------------------------------------------------------
// 256x256 NT GEMM via tile_engine (grid (DIM/256, N_ROWS/256) = 256 blocks =
// exactly 1 block/CU, no tail). EPI 1/4 as before.
template <int EPI>
__global__ __launch_bounds__(512, 2)
void gemm_nt_256(const __hip_bfloat16* __restrict__ A,
                 const __hip_bfloat16* __restrict__ B,
                 void* __restrict__ Cv,
                 const float* __restrict__ bias,
                 float* __restrict__ stats) {
    __shared__ __align__(16) char smem[2 * (256 * 128 + 32768)];   // 128 KB
    tile_engine<256, EPI>(A, B, smem,
                          (size_t)blockIdx.y * 256, (size_t)blockIdx.x * 256,
                          nullptr, Cv, bias, stats, 0, 0);
}

// ---------------------------------------------------------------------------
// Classifier GEMM on the same engine: out[8192,751] = z2b @ wcs^T + lb.
// BM=128 tile -> grid (NPAD/256=3, N_ROWS/128=64) = 192 blocks, 1 clean
// round. EPI=5: fp32 store, col<NCLS guard, row stride NCLS.
__global__ __launch_bounds__(512, 2)
void gemm_cls(const __hip_bfloat16* __restrict__ A,
              const __hip_bfloat16* __restrict__ B,
              float* __restrict__ out,
              const float* __restrict__ lb) {
    __shared__ __align__(16) char smem[2 * (128 * 128 + 32768)];   // 96 KB
    tile_engine<128, 5>(A, B, smem,
                        (size_t)blockIdx.y * 128, (size_t)blockIdx.x * 256,
                        nullptr, (void*)out, lb, nullptr, NCLS, NCLS);
}

// ---------------------------------------------------------------------------
// R12 topk: R9-exact per-row algorithm (1 wave per row, 64-thread blocks,
// LDS scan buffer + LDS 12-round selection -- measured best at 178 us),
// plus a double-buffered PREFETCH in the scan loop: the it+1 vector is
// loaded before processing it, hiding global-load latency. Element
// processing ORDER is unchanged -> per-lane top-6 (incl. duplicate-tie
// survivors), selection, gap test, and rescore are bit-identical to R9.
__global__ __launch_bounds__(64)
void topk_kernel(const __hip_bfloat16* __restrict__ S,
                 const float* __restrict__ x,
                 const double* __restrict__ invn,
                 int* __restrict__ idx6) {
    int row = blockIdx.x, lane = threadIdx.x;   // 64 threads
    const bf16x8* Sr8 = (const bf16x8*)(S + (size_t)row * N_ROWS);
    float bv[6]; int bi6[6];
#pragma unroll
    for (int t = 0; t < 6; ++t) { bv[t] = -1e30f; bi6[t] = -1; }
    float vmin = -1e30f;
    bf16x8 cur = Sr8[lane];                     // prefetch it=0
    for (int it = 0; it < N_ROWS / (64 * 8); ++it) {
        bf16x8 nxt;
        if (it + 1 < N_ROWS / (64 * 8)) nxt = Sr8[(it + 1) * 64 + lane];
        int c8 = it * 64 + lane;
#pragma unroll
        for (int u = 0; u < 8; ++u) {
            float v = bf16_to_f32(cur[u]);
            if (v > vmin) {
                int ms = 0; float mv = bv[0];
#pragma unroll
                for (int t = 1; t < 6; ++t) if (bv[t] < mv) { mv = bv[t]; ms = t; }
                bv[ms] = v; bi6[ms] = c8 * 8 + u;
                vmin = bv[0];
#pragma unroll
                for (int t = 1; t < 6; ++t) vmin = fminf(vmin, bv[t]);
            }
        }
        cur = nxt;
    }
    __shared__ float sv[384];
    __shared__ int   si[384];
    __shared__ float topv[NCAND];
    __shared__ int   topi[NCAND];
#pragma unroll
    for (int t = 0; t < 6; ++t) { sv[lane * 6 + t] = bv[t]; si[lane * 6 + t] = bi6[t]; }
    __syncthreads();
    for (int t = 0; t < NCAND; ++t) {
        float m = -1e30f; int mpos = -1, midx = 0x7fffffff;
        for (int e = lane; e < 384; e += 64) {
            float v = sv[e]; int ix = si[e];
            if (v > m || (v == m && ix < midx)) { m = v; mpos = e; midx = ix; }
        }
#pragma unroll
        for (int off = 32; off; off >>= 1) {
            float ov = __shfl_xor(m, off);
            int   op = __shfl_xor(mpos, off);
            int   oi = __shfl_xor(midx, off);
            if (ov > m || (ov == m && oi < midx)) { m = ov; mpos = op; midx = oi; }
        }
        if (lane == 0) {
            topv[t] = m; topi[t] = midx;
            sv[mpos] = -1e30f;
        }
        __syncthreads();
    }
    // gap test (block == 1 wave; LDS values visible after the barrier above)
    if (topv[KNN - 1] - topv[KNN] >= GAP_THRESH) {
        if (lane == 0) {
#pragma unroll
            for (int t = 0; t < KNN; ++t) idx6[row * KNN + t] = topi[t];
        }
        return;
    }
    // ---- fused exact rescore (bit-identical to R9) ----
    __shared__ double simv[NCAND];
    float4 xr[8];
    const float4* xrow4 = (const float4*)(x + (size_t)row * DIM);
#pragma unroll
    for (int i = 0; i < 8; ++i) xr[i] = xrow4[lane + 64 * i];
    for (int t = 0; t < NCAND; ++t) {
        int j = topi[t];
        if (j == row) { if (lane == 0) simv[t] = 1e30; continue; }  // self: rank 1
        const float4* xj4 = (const float4*)(x + (size_t)j * DIM);
        double s = 0.0;
#pragma unroll
        for (int i = 0; i < 8; ++i) {
            float4 a = xj4[lane + 64 * i], bq = xr[i];
            s += (double)a.x * bq.x + (double)a.y * bq.y +
                 (double)a.z * bq.z + (double)a.w * bq.w;
        }
#pragma unroll
        for (int off = 32; off; off >>= 1) s += __shfl_xor(s, off);
        if (lane == 0) simv[t] = s * invn[row] * invn[j];
    }
    __syncthreads();
    if (lane == 0) {
        double vals[NCAND]; int idxs[NCAND];
        for (int t = 0; t < NCAND; ++t) { vals[t] = simv[t]; idxs[t] = topi[t]; }
        for (int t = 0; t < KNN; ++t) {
            int best = 0; double bvv = -1e300; int bji = 0x7fffffff;
            for (int e = 0; e < NCAND; ++e) {
                if (vals[e] > bvv || (vals[e] == bvv && idxs[e] < bji)) {
                    bvv = vals[e]; best = e; bji = idxs[e];
                }
            }
            idx6[row * KNN + t] = idxs[best];
            vals[best] = -1e300;
        }
    }
}

// ---------------------------------------------------------------------------
// GIN aggregation with reciprocal mask: h0 = 1.3*x_i + sum reciprocal x_j -> bf16
__global__ void aggregate_kernel(const float* __restrict__ x,
                                 const int* __restrict__ idx6,
                                 __hip_bfloat16* __restrict__ h0) {
    int row = blockIdx.x, tid = threadIdx.x;   // 256 threads
    __shared__ int nb[KNN];
    __shared__ int fl[KNN];
    if (tid < KNN) {
        int j = idx6[row * KNN + tid];
        nb[tid] = j;
        int f = 0;
        for (int t = 0; t < KNN; ++t) if (idx6[j * KNN + t] == row) f = 1;
        fl[tid] = f;
    }
    __syncthreads();
    int f0 = tid * 8;
    const float4* xr4 = (const float4*)(x + (size_t)row * DIM + f0);
    float4 a0 = xr4[0], a1 = xr4[1];
    float acc[8] = {1.3f * a0.x, 1.3f * a0.y, 1.3f * a0.z, 1.3f * a0.w,
                    1.3f * a1.x, 1.3f * a1.y, 1.3f * a1.z, 1.3f * a1.w};
    for (int t = 0; t < KNN; ++t) {
        if (fl[t]) {
            const float4* xj4 = (const float4*)(x + (size_t)nb[t] * DIM + f0);
            float4 b0 = xj4[0], b1 = xj4[1];
            acc[0] += b0.x; acc[1] += b0.y; acc[2] += b0.z; acc[3] += b0.w;
            acc[4] += b1.x; acc[5] += b1.y; acc[6] += b1.z; acc[7] += b1.w;
        }
    }
#pragma unroll
    for (int u = 0; u < 8; ++u)
        h0[(size_t)row * DIM + f0 + u] = __float2bfloat16(acc[u]);
}

// ---------------------------------------------------------------------------
// Fold BN into classifier (bn_finalize fused in): per column k,
//   mean = s1/N, var = s2/N - mean^2, sc = gamma/sqrt(var+eps),
//   shift = beta - mean*sc;  wcs[c,k] = wc[c,k]*sc (bf16, zero-padded rows),
//   lb[c] = sum_k shift[k]*wc[c,k].
__global__ void wc_fold_kernel(const float* __restrict__ wc,
                               const float* __restrict__ stats,
                               const float* __restrict__ gamma,
                               const float* __restrict__ beta,
                               __hip_bfloat16* __restrict__ wcs,
                               float* __restrict__ lb) {
    int r = blockIdx.x, tid = threadIdx.x;          // 768 blocks x 256
    int k0 = tid * 8;
    float part = 0.f;
    if (r < NCLS) {
#pragma unroll
        for (int u = 0; u < 8; ++u) {
            int k = k0 + u;
            float mean = stats[k] * (1.0f / 8192.0f);
            float var  = stats[DIM + k] * (1.0f / 8192.0f) - mean * mean;
            float sc   = gamma[k] / sqrtf(var + 1e-5f);
            float sh   = beta[k] - mean * sc;
            float w = wc[(size_t)r * DIM + k];
            wcs[(size_t)r * DIM + k] = __float2bfloat16(w * sc);
            part += w * sh;
        }
    } else {
#pragma unroll
        for (int u = 0; u < 8; ++u)
            wcs[(size_t)r * DIM + k0 + u] = __float2bfloat16(0.f);
    }
    __shared__ float red[256];
    red[tid] = part; __syncthreads();
    for (int off = 128; off; off >>= 1) {
        if (tid < off) red[tid] += red[tid + off];
        __syncthreads();
    }
    if (tid == 0) lb[r] = red[0];
}

// ---------------------------------------------------------------------------
extern "C" void kernel_launch(void* const* d_in, const int* in_sizes, int n_in,
                              void* d_out, int out_size, void* d_ws, size_t ws_size,
                              hipStream_t stream) {
    const float* x     = (const float*)d_in[0];
    const float* w1    = (const float*)d_in[1];
    const float* b1    = (const float*)d_in[2];
    const float* w2    = (const float*)d_in[3];
    const float* b2    = (const float*)d_in[4];
    const float* gamma = (const float*)d_in[5];
    const float* beta  = (const float*)d_in[6];
    const float* wc    = (const float*)d_in[7];
    float* out = (float*)d_out;

    char* ws = (char*)d_ws;
    size_t off = 0;
    auto alloc = [&](size_t bytes) -> void* {
        void* p = ws + off;
        off += (bytes + 255) & ~(size_t)255;
        return p;
    };

    __hip_bfloat16* xnb  = (__hip_bfloat16*)alloc((size_t)N_ROWS * DIM * 2);    // 32 MB (reused: h0)
    __hip_bfloat16* S    = (__hip_bfloat16*)alloc((size_t)N_ROWS * N_ROWS * 2); // 128 MB (reused: z1, z2b)
    double*         invn = (double*)alloc((size_t)N_ROWS * 8);
    int*            idx6 = (int*)alloc((size_t)N_ROWS * KNN * 4);
    __hip_bfloat16* w1b  = (__hip_bfloat16*)alloc((size_t)DIM * DIM * 2);
    __hip_bfloat16* w2b  = (__hip_bfloat16*)alloc((size_t)DIM * DIM * 2);
    __hip_bfloat16* wcs  = (__hip_bfloat16*)alloc((size_t)NPAD * DIM * 2);
    float*          lb   = (float*)alloc((size_t)NPAD * 4);
    float*          stats = (float*)alloc((size_t)4 * DIM * 4);

    __hip_bfloat16* h0  = xnb;                          // xn dead after syrk
    __hip_bfloat16* z1  = S;                            // S dead after topk
    __hip_bfloat16* z2b = S + (size_t)N_ROWS * DIM;     // next 32 MB of S region

    hipMemsetAsync(stats, 0, 2 * DIM * sizeof(float), stream);

    // normalize + both weight conversions, one launch
    prep_kernel<<<2 * N_ROWS, 256, 0, stream>>>(x, xnb, invn, w1, w2, w1b, w2b);

    // S = xn xn^T: 64 diagonal half-blocks + 496 upper 256^2 tiles (XCD-chunked)
    gemm_syrk<<<560, 512, 0, stream>>>(xnb, S);

    // top-6 (+ fused exact rescore), 1 wave per row (R9 packaging, measured best)
    topk_kernel<<<N_ROWS, 64, 0, stream>>>(S, x, invn, idx6);
    aggregate_kernel<<<N_ROWS, 256, 0, stream>>>(x, idx6, h0);

    // z1 = relu(h0 @ w1^T + b1)   [bf16]
    gemm_nt_256<1><<<dim3(DIM / 256, N_ROWS / 256), 512, 0, stream>>>(
        h0, w1b, (void*)z1, b1, nullptr);
    // z2b = h@w2^T + b2 [bf16] with fused BN column stats
    gemm_nt_256<4><<<dim3(DIM / 256, N_ROWS / 256), 512, 0, stream>>>(
        z1, w2b, (void*)z2b, b2, stats);

    // fold BN into classifier weights (bn_finalize fused)
    wc_fold_kernel<<<NPAD, 256, 0, stream>>>(wc, stats, gamma, beta, wcs, lb);

    // logits = (z2*scale+shift) @ wc^T = z2b @ wcs^T + lb   [fp32, col<751]
    gemm_cls<<<dim3(NPAD / 256, N_ROWS / 128), 512, 0, stream>>>(
        z2b, wcs, out, lb);
}